// Round 12
// baseline (122.715 us; speedup 1.0000x reference)
//
#include <hip/hip_runtime.h>

#define D 128
#define RPB 128   // rows per block

typedef float f32x4 __attribute__((ext_vector_type(4)));

// ---------------------------------------------------------------------------
// DPP half-wave (32-lane) sum. Pure VALU (no DS pipe): row_shr 1,2,4,8 then
// row_bcast:15 into rows 1,3. Result valid in wave-lanes 31 and 63.
// ---------------------------------------------------------------------------
__device__ __forceinline__ float dpp_half_sum(float v) {
    #define DPP_STEP(ctrl, rowmask)                                           \
        v += __int_as_float(__builtin_amdgcn_update_dpp(                      \
                 0, __float_as_int(v), (ctrl), (rowmask), 0xF, true))
    DPP_STEP(0x111, 0xF);   // row_shr:1
    DPP_STEP(0x112, 0xF);   // row_shr:2
    DPP_STEP(0x114, 0xF);   // row_shr:4
    DPP_STEP(0x118, 0xF);   // row_shr:8  -> lane15 of each 16-row has row sum
    DPP_STEP(0x142, 0xA);   // row_bcast:15 -> rows 1,3 add prev row's lane15
    #undef DPP_STEP
    return v;               // lanes 31, 63 hold their half's sum
}

// ---------------------------------------------------------------------------
// Kernel 0 (one block): fold the linear chains into ws.
//   ws[0..383]    : J_enc [3][128]  = We3@We2@We1
//   ws[384..386]  : b_enc [3]       = We3@(We2@be1 + be2) + be3
//   ws[512..1023] : J_dec4 [128][4] = (J_dec[c][0..2], b_dec[c])
// ---------------------------------------------------------------------------
__global__ __launch_bounds__(256) void fuse_weights(
    const float* __restrict__ We1, const float* __restrict__ be1,
    const float* __restrict__ We2, const float* __restrict__ be2,
    const float* __restrict__ We3, const float* __restrict__ be3,
    const float* __restrict__ Wd1, const float* __restrict__ bd1,
    const float* __restrict__ Wd2, const float* __restrict__ bd2,
    const float* __restrict__ Wd3, const float* __restrict__ bd3,
    float* __restrict__ ws)
{
    __shared__ float A1[3][64];   // We3@We2
    __shared__ float B1[64][3];   // Wd2@Wd1
    __shared__ float t2d[64];     // Wd2@bd1 + bd2
    const int t = threadIdx.x;

    if (t < 192) {
        {   int r = t >> 6, c = t & 63;
            float s = 0.f;
            #pragma unroll 8
            for (int i = 0; i < 32; ++i) s += We3[r * 32 + i] * We2[i * 64 + c];
            A1[r][c] = s;
        }
        {   int o = t / 3, l = t - o * 3;
            float s = 0.f;
            #pragma unroll 8
            for (int i = 0; i < 32; ++i) s += Wd2[o * 32 + i] * Wd1[i * 3 + l];
            B1[o][l] = s;
        }
    } else {
        int i = t - 192;
        float s = bd2[i];
        #pragma unroll 8
        for (int j = 0; j < 32; ++j) s += Wd2[i * 32 + j] * bd1[j];
        t2d[i] = s;
    }
    __syncthreads();

    for (int e = t; e < 3 * D; e += 256) {
        int r = e >> 7, c = e & 127;
        float s = 0.f;
        #pragma unroll 8
        for (int j = 0; j < 64; ++j) s += A1[r][j] * We1[j * D + c];
        ws[e] = s;
    }
    if (t < 3) {
        float s = be3[t];
        #pragma unroll 8
        for (int j = 0; j < 64; ++j) s += A1[t][j] * be1[j];
        #pragma unroll 8
        for (int i = 0; i < 32; ++i) s += We3[t * 32 + i] * be2[i];
        ws[384 + t] = s;
    }
    if (t < 128) {
        float s0 = 0.f, s1 = 0.f, s2 = 0.f, sb = bd3[t];
        #pragma unroll 8
        for (int j = 0; j < 64; ++j) {
            float w = Wd3[t * 64 + j];
            s0 += w * B1[j][0];
            s1 += w * B1[j][1];
            s2 += w * B1[j][2];
            sb += w * t2d[j];
        }
        ws[512 + t * 4 + 0] = s0;
        ws[512 + t * 4 + 1] = s1;
        ws[512 + t * 4 + 2] = s2;
        ws[512 + t * 4 + 3] = sb;
    }
}

// ---------------------------------------------------------------------------
// Kernel 1 (READ-phase, phase-pure): x,dx -> z, dz, dzb. 128 rows/block.
// Plain coalesced f32x4 reads (L3-retained across graph replays, R11 A/B),
// DPP reduce (VALU, R7 A/B), theta once per row (R6), small outputs stored
// PLAIN (stay cache-hot for dec + harness).
// ---------------------------------------------------------------------------
__global__ __launch_bounds__(256) void enc_k(
    const float* __restrict__ x, const float* __restrict__ dx,
    const float* __restrict__ EW, const float* __restrict__ Eb,
    const float* __restrict__ ws, float* __restrict__ out, int nrows)
{
    __shared__ alignas(16) float sz[RPB * 3];
    __shared__ alignas(16) float sdz[RPB * 3];
    __shared__ alignas(16) float sdzb[RPB * 3];
    __shared__ alignas(16) float sew[69];

    const int t    = threadIdx.x;
    const int lane = t & 31;
    const int half = t >> 5;

    if (t < 69) sew[t] = (t < 66) ? EW[t] : Eb[t - 66];

    const f32x4 je0 = *((const f32x4*)(ws +   0) + lane);
    const f32x4 je1 = *((const f32x4*)(ws + 128) + lane);
    const f32x4 je2 = *((const f32x4*)(ws + 256) + lane);
    const float benc0 = ws[384], benc1 = ws[385], benc2 = ws[386];

    const int base = blockIdx.x * RPB;
    const int rem  = nrows - base;

    // ---- P1: x -> z ----
    #pragma unroll 4
    for (int i = 0; i < RPB / 8; ++i) {
        const int r2  = i * 8 + half;
        const int row = base + r2;
        if (row >= nrows) continue;
        const f32x4 xv = ((const f32x4*)(x + (size_t)row * D))[lane];
        float z0 = je0.x*xv.x + je0.y*xv.y + je0.z*xv.z + je0.w*xv.w;
        float z1 = je1.x*xv.x + je1.y*xv.y + je1.z*xv.z + je1.w*xv.w;
        float z2 = je2.x*xv.x + je2.y*xv.y + je2.z*xv.z + je2.w*xv.w;
        z0 = dpp_half_sum(z0);
        z1 = dpp_half_sum(z1);
        z2 = dpp_half_sum(z2);
        if (lane == 31) {
            sz[r2 * 3 + 0] = z0 + benc0;
            sz[r2 * 3 + 1] = z1 + benc1;
            sz[r2 * 3 + 2] = z2 + benc2;
        }
    }

    // ---- P2: dx -> dz ----
    #pragma unroll 4
    for (int i = 0; i < RPB / 8; ++i) {
        const int r2  = i * 8 + half;
        const int row = base + r2;
        if (row >= nrows) continue;
        const f32x4 dv = ((const f32x4*)(dx + (size_t)row * D))[lane];
        float d0 = je0.x*dv.x + je0.y*dv.y + je0.z*dv.z + je0.w*dv.w;
        float d1 = je1.x*dv.x + je1.y*dv.y + je1.z*dv.z + je1.w*dv.w;
        float d2 = je2.x*dv.x + je2.y*dv.y + je2.z*dv.z + je2.w*dv.w;
        d0 = dpp_half_sum(d0);
        d1 = dpp_half_sum(d1);
        d2 = dpp_half_sum(d2);
        if (lane == 31) {
            sdz[r2 * 3 + 0] = d0;
            sdz[r2 * 3 + 1] = d1;
            sdz[r2 * 3 + 2] = d2;
        }
    }

    __syncthreads();

    // ---- P3: theta/dzb, one row per thread ----
    if (t < RPB && t < rem) {
        const float z0 = sz[t * 3 + 0];
        const float z1 = sz[t * 3 + 1];
        const float z2 = sz[t * 3 + 2];

        const float q00 = z0*z0, q01 = z0*z1, q02 = z0*z2;
        const float q11 = z1*z1, q12 = z1*z2, q22 = z2*z2;
        float th[19];
        th[0]=z0;  th[1]=z1;  th[2]=z2;
        th[3]=q00; th[4]=q01; th[5]=q02; th[6]=q11; th[7]=q12; th[8]=q22;
        th[9]=q00*z0;  th[10]=q00*z1; th[11]=q00*z2;
        th[12]=q11*z0; th[13]=q12*z0; th[14]=q22*z0;
        th[15]=q11*z1; th[16]=q11*z2; th[17]=q22*z1; th[18]=q22*z2;

        float b0 = sew[66] + sew[0]  + sew[1]  + sew[2];
        float b1 = sew[67] + sew[22] + sew[23] + sew[24];
        float b2 = sew[68] + sew[44] + sew[45] + sew[46];
        #pragma unroll
        for (int k = 0; k < 19; ++k) {
            b0 += sew[3  + k] * th[k];
            b1 += sew[25 + k] * th[k];
            b2 += sew[47 + k] * th[k];
        }
        sdzb[t * 3 + 0] = b0;
        sdzb[t * 3 + 1] = b1;
        sdzb[t * 3 + 2] = b2;
    }

    __syncthreads();

    // ---- P3b: coalesced PLAIN stores (cache-hot for dec + harness) ----
    if (rem >= RPB) {
        if (t < RPB * 3 / 4) {   // 96 f32x4 per stream
            ((f32x4*)(out + (size_t)base * 3))[t]                     = ((const f32x4*)sz)[t];
            ((f32x4*)(out + 3 * (size_t)nrows + (size_t)base * 3))[t] = ((const f32x4*)sdz)[t];
            ((f32x4*)(out + 6 * (size_t)nrows + (size_t)base * 3))[t] = ((const f32x4*)sdzb)[t];
        }
    } else {
        for (int e = t; e < rem * 3; e += 256) {
            out[(size_t)base * 3 + e]                     = sz[e];
            out[3 * (size_t)nrows + (size_t)base * 3 + e] = sdz[e];
            out[6 * (size_t)nrows + (size_t)base * 3 + e] = sdzb[e];
        }
    }
}

// ---------------------------------------------------------------------------
// Kernel 2 (WRITE-phase, phase-pure): z,dzb (L2-hot) -> xb, dxb NT streams.
// 128 rows/block; ~40 VGPR pure write-streamer (matches fill-kernel profile).
// ---------------------------------------------------------------------------
__global__ __launch_bounds__(256) void dec_k(
    const float* __restrict__ ws, const float* __restrict__ out_ro,
    float* __restrict__ out, int nrows)
{
    __shared__ alignas(16) float sz[RPB * 3];
    __shared__ alignas(16) float sdzb[RPB * 3];

    const int t    = threadIdx.x;
    const int lane = t & 31;
    const int half = t >> 5;

    const f32x4 jd0 = *((const f32x4*)(ws + 512) + lane * 4 + 0);
    const f32x4 jd1 = *((const f32x4*)(ws + 512) + lane * 4 + 1);
    const f32x4 jd2 = *((const f32x4*)(ws + 512) + lane * 4 + 2);
    const f32x4 jd3 = *((const f32x4*)(ws + 512) + lane * 4 + 3);

    const int base = blockIdx.x * RPB;
    const int rem  = nrows - base;

    // ---- stage z, dzb for this block's rows into LDS (coalesced) ----
    if (rem >= RPB) {
        if (t < RPB * 3 / 4) {   // 96 f32x4 per stream
            ((f32x4*)sz)[t]   = ((const f32x4*)(out_ro + (size_t)base * 3))[t];
            ((f32x4*)sdzb)[t] = ((const f32x4*)(out_ro + 6 * (size_t)nrows + (size_t)base * 3))[t];
        }
    } else {
        for (int e = t; e < rem * 3; e += 256) {
            sz[e]   = out_ro[(size_t)base * 3 + e];
            sdzb[e] = out_ro[6 * (size_t)nrows + (size_t)base * 3 + e];
        }
    }
    __syncthreads();

    // ---- xb NT-write stream ----
    float* __restrict__ xbout = out + 9 * (size_t)nrows;
    #pragma unroll 4
    for (int i = 0; i < RPB / 8; ++i) {
        const int r2  = i * 8 + half;
        const int row = base + r2;
        if (row >= nrows) continue;
        const float z0 = sz[r2 * 3 + 0];
        const float z1 = sz[r2 * 3 + 1];
        const float z2 = sz[r2 * 3 + 2];
        f32x4 v;
        v.x = jd0.x*z0 + jd0.y*z1 + jd0.z*z2 + jd0.w;
        v.y = jd1.x*z0 + jd1.y*z1 + jd1.z*z2 + jd1.w;
        v.z = jd2.x*z0 + jd2.y*z1 + jd2.z*z2 + jd2.w;
        v.w = jd3.x*z0 + jd3.y*z1 + jd3.z*z2 + jd3.w;
        __builtin_nontemporal_store(v, (f32x4*)(xbout + (size_t)row * D) + lane);
    }

    // ---- dxb NT-write stream ----
    float* __restrict__ dxbout = out + 137 * (size_t)nrows;
    #pragma unroll 4
    for (int i = 0; i < RPB / 8; ++i) {
        const int r2  = i * 8 + half;
        const int row = base + r2;
        if (row >= nrows) continue;
        const float b0 = sdzb[r2 * 3 + 0];
        const float b1 = sdzb[r2 * 3 + 1];
        const float b2 = sdzb[r2 * 3 + 2];
        f32x4 v;
        v.x = jd0.x*b0 + jd0.y*b1 + jd0.z*b2;
        v.y = jd1.x*b0 + jd1.y*b1 + jd1.z*b2;
        v.z = jd2.x*b0 + jd2.y*b1 + jd2.z*b2;
        v.w = jd3.x*b0 + jd3.y*b1 + jd3.z*b2;
        __builtin_nontemporal_store(v, (f32x4*)(dxbout + (size_t)row * D) + lane);
    }
}

extern "C" void kernel_launch(void* const* d_in, const int* in_sizes, int n_in,
                              void* d_out, int out_size, void* d_ws, size_t ws_size,
                              hipStream_t stream) {
    const float* x   = (const float*)d_in[0];
    const float* dx  = (const float*)d_in[1];
    const float* We1 = (const float*)d_in[2];
    const float* be1 = (const float*)d_in[3];
    const float* We2 = (const float*)d_in[4];
    const float* be2 = (const float*)d_in[5];
    const float* We3 = (const float*)d_in[6];
    const float* be3 = (const float*)d_in[7];
    const float* Wd1 = (const float*)d_in[8];
    const float* bd1 = (const float*)d_in[9];
    const float* Wd2 = (const float*)d_in[10];
    const float* bd2 = (const float*)d_in[11];
    const float* Wd3 = (const float*)d_in[12];
    const float* bd3 = (const float*)d_in[13];
    const float* EW  = (const float*)d_in[14];
    const float* Eb  = (const float*)d_in[15];

    float* ws  = (float*)d_ws;
    float* out = (float*)d_out;
    const int nrows = in_sizes[0] / D;             // 262144
    const int nblk  = (nrows + RPB - 1) / RPB;     // 2048

    fuse_weights<<<1, 256, 0, stream>>>(We1, be1, We2, be2, We3, be3,
                                        Wd1, bd1, Wd2, bd2, Wd3, bd3, ws);

    enc_k<<<nblk, 256, 0, stream>>>(x, dx, EW, Eb, ws, out, nrows);

    dec_k<<<nblk, 256, 0, stream>>>(ws, out, out, nrows);
}

// Round 13
// 122.335 us; speedup vs baseline: 1.0031x; 1.0031x over previous
//
#include <hip/hip_runtime.h>

#define D 128
#define RPB 128   // rows per block

typedef float f32x4 __attribute__((ext_vector_type(4)));

// ---------------------------------------------------------------------------
// DPP half-wave (32-lane) sum. Pure VALU (no DS pipe): row_shr 1,2,4,8 then
// row_bcast:15 into rows 1,3. Result valid in wave-lanes 31 and 63.
// ---------------------------------------------------------------------------
__device__ __forceinline__ float dpp_half_sum(float v) {
    #define DPP_STEP(ctrl, rowmask)                                           \
        v += __int_as_float(__builtin_amdgcn_update_dpp(                      \
                 0, __float_as_int(v), (ctrl), (rowmask), 0xF, true))
    DPP_STEP(0x111, 0xF);   // row_shr:1
    DPP_STEP(0x112, 0xF);   // row_shr:2
    DPP_STEP(0x114, 0xF);   // row_shr:4
    DPP_STEP(0x118, 0xF);   // row_shr:8  -> lane15 of each 16-row has row sum
    DPP_STEP(0x142, 0xA);   // row_bcast:15 -> rows 1,3 add prev row's lane15
    #undef DPP_STEP
    return v;               // lanes 31, 63 hold their half's sum
}

// ---------------------------------------------------------------------------
// Kernel 0 (one block): fold the linear chains into ws.
//   ws[0..383]    : J_enc [3][128]  = We3@We2@We1
//   ws[384..386]  : b_enc [3]       = We3@(We2@be1 + be2) + be3
//   ws[512..1023] : J_dec4 [128][4] = (J_dec[c][0..2], b_dec[c])
// ---------------------------------------------------------------------------
__global__ __launch_bounds__(256) void fuse_weights(
    const float* __restrict__ We1, const float* __restrict__ be1,
    const float* __restrict__ We2, const float* __restrict__ be2,
    const float* __restrict__ We3, const float* __restrict__ be3,
    const float* __restrict__ Wd1, const float* __restrict__ bd1,
    const float* __restrict__ Wd2, const float* __restrict__ bd2,
    const float* __restrict__ Wd3, const float* __restrict__ bd3,
    float* __restrict__ ws)
{
    __shared__ float A1[3][64];   // We3@We2
    __shared__ float B1[64][3];   // Wd2@Wd1
    __shared__ float t2d[64];     // Wd2@bd1 + bd2
    const int t = threadIdx.x;

    if (t < 192) {
        {   int r = t >> 6, c = t & 63;
            float s = 0.f;
            #pragma unroll 8
            for (int i = 0; i < 32; ++i) s += We3[r * 32 + i] * We2[i * 64 + c];
            A1[r][c] = s;
        }
        {   int o = t / 3, l = t - o * 3;
            float s = 0.f;
            #pragma unroll 8
            for (int i = 0; i < 32; ++i) s += Wd2[o * 32 + i] * Wd1[i * 3 + l];
            B1[o][l] = s;
        }
    } else {
        int i = t - 192;
        float s = bd2[i];
        #pragma unroll 8
        for (int j = 0; j < 32; ++j) s += Wd2[i * 32 + j] * bd1[j];
        t2d[i] = s;
    }
    __syncthreads();

    for (int e = t; e < 3 * D; e += 256) {
        int r = e >> 7, c = e & 127;
        float s = 0.f;
        #pragma unroll 8
        for (int j = 0; j < 64; ++j) s += A1[r][j] * We1[j * D + c];
        ws[e] = s;
    }
    if (t < 3) {
        float s = be3[t];
        #pragma unroll 8
        for (int j = 0; j < 64; ++j) s += A1[t][j] * be1[j];
        #pragma unroll 8
        for (int i = 0; i < 32; ++i) s += We3[t * 32 + i] * be2[i];
        ws[384 + t] = s;
    }
    if (t < 128) {
        float s0 = 0.f, s1 = 0.f, s2 = 0.f, sb = bd3[t];
        #pragma unroll 8
        for (int j = 0; j < 64; ++j) {
            float w = Wd3[t * 64 + j];
            s0 += w * B1[j][0];
            s1 += w * B1[j][1];
            s2 += w * B1[j][2];
            sb += w * t2d[j];
        }
        ws[512 + t * 4 + 0] = s0;
        ws[512 + t * 4 + 1] = s1;
        ws[512 + t * 4 + 2] = s2;
        ws[512 + t * 4 + 3] = sb;
    }
}

// ---------------------------------------------------------------------------
// Main kernel (R11 structure): 128 contiguous rows per block, fused phases.
// NEW vs R11: block-granular L3 partition on the read path. Blocks with
// (blockIdx.x & 7) == 7 use NT loads (1/8 of x/dx = 33.5MB never cached);
// the other 7/8 (~235MB) then FITS the 256MB L3 and stays resident across
// graph replays -> near-zero HBM read traffic for those blocks.
// [R8 FETCH=134MB proved ~50% replay retention with NO partition; this
//  removes the thrash at the margin.]
// NT stores on all output streams (R7/R8 A/B). DPP reduce (R7).
// Output layout: z@0 [N,3], dz@3N, dzb@6N, xb@9N [N,128], dxb@137N [N,128]
// ---------------------------------------------------------------------------
__global__ __launch_bounds__(256) void sindy_all(
    const float* __restrict__ x, const float* __restrict__ dx,
    const float* __restrict__ EW, const float* __restrict__ Eb,
    const float* __restrict__ ws, float* __restrict__ out, int nrows)
{
    __shared__ alignas(16) float sz[RPB * 3];     // z   [128][3]
    __shared__ alignas(16) float sdz[RPB * 3];    // dz  [128][3]
    __shared__ alignas(16) float sdzb[RPB * 3];   // dzb [128][3]
    __shared__ alignas(16) float sew[69];         // EW[66], Eb[3]

    const int t    = threadIdx.x;
    const int lane = t & 31;
    const int half = t >> 5;

    if (t < 69) sew[t] = (t < 66) ? EW[t] : Eb[t - 66];

    const f32x4 je0 = *((const f32x4*)(ws +   0) + lane);
    const f32x4 je1 = *((const f32x4*)(ws + 128) + lane);
    const f32x4 je2 = *((const f32x4*)(ws + 256) + lane);
    const float benc0 = ws[384], benc1 = ws[385], benc2 = ws[386];
    const f32x4 jd0 = *((const f32x4*)(ws + 512) + lane * 4 + 0);
    const f32x4 jd1 = *((const f32x4*)(ws + 512) + lane * 4 + 1);
    const f32x4 jd2 = *((const f32x4*)(ws + 512) + lane * 4 + 2);
    const f32x4 jd3 = *((const f32x4*)(ws + 512) + lane * 4 + 3);

    const int base = blockIdx.x * RPB;
    const int rem  = nrows - base;
    const bool ntblk = ((blockIdx.x & 7) == 7);   // 1/8 of blocks: NT reads

    // ---- P1: x -> z ---- / ---- P2: dx -> dz ----
    #define ENC_PHASE(SRC, DST, ADD0, ADD1, ADD2, NT)                         \
    _Pragma("unroll 4")                                                       \
    for (int i = 0; i < RPB / 8; ++i) {                                       \
        const int r2  = i * 8 + half;                                         \
        const int row = base + r2;                                            \
        if (row >= nrows) continue;                                           \
        f32x4 v_;                                                             \
        if (NT) v_ = __builtin_nontemporal_load((const f32x4*)(SRC + (size_t)row * D) + lane); \
        else    v_ = ((const f32x4*)(SRC + (size_t)row * D))[lane];           \
        float s0 = je0.x*v_.x + je0.y*v_.y + je0.z*v_.z + je0.w*v_.w;         \
        float s1 = je1.x*v_.x + je1.y*v_.y + je1.z*v_.z + je1.w*v_.w;         \
        float s2 = je2.x*v_.x + je2.y*v_.y + je2.z*v_.z + je2.w*v_.w;         \
        s0 = dpp_half_sum(s0);                                                \
        s1 = dpp_half_sum(s1);                                                \
        s2 = dpp_half_sum(s2);                                                \
        if (lane == 31) {                                                     \
            DST[r2 * 3 + 0] = s0 + (ADD0);                                    \
            DST[r2 * 3 + 1] = s1 + (ADD1);                                    \
            DST[r2 * 3 + 2] = s2 + (ADD2);                                    \
        }                                                                     \
    }

    if (ntblk) {
        ENC_PHASE(x,  sz,  benc0, benc1, benc2, true)
        ENC_PHASE(dx, sdz, 0.f,   0.f,   0.f,   true)
    } else {
        ENC_PHASE(x,  sz,  benc0, benc1, benc2, false)
        ENC_PHASE(dx, sdz, 0.f,   0.f,   0.f,   false)
    }
    #undef ENC_PHASE

    __syncthreads();

    // ---- P3: theta/dzb, one row per thread ----
    if (t < RPB && t < rem) {
        const float z0 = sz[t * 3 + 0];
        const float z1 = sz[t * 3 + 1];
        const float z2 = sz[t * 3 + 2];

        const float q00 = z0*z0, q01 = z0*z1, q02 = z0*z2;
        const float q11 = z1*z1, q12 = z1*z2, q22 = z2*z2;
        float th[19];
        th[0]=z0;  th[1]=z1;  th[2]=z2;
        th[3]=q00; th[4]=q01; th[5]=q02; th[6]=q11; th[7]=q12; th[8]=q22;
        th[9]=q00*z0;  th[10]=q00*z1; th[11]=q00*z2;
        th[12]=q11*z0; th[13]=q12*z0; th[14]=q22*z0;
        th[15]=q11*z1; th[16]=q11*z2; th[17]=q22*z1; th[18]=q22*z2;

        float b0 = sew[66] + sew[0]  + sew[1]  + sew[2];
        float b1 = sew[67] + sew[22] + sew[23] + sew[24];
        float b2 = sew[68] + sew[44] + sew[45] + sew[46];
        #pragma unroll
        for (int k = 0; k < 19; ++k) {
            b0 += sew[3  + k] * th[k];
            b1 += sew[25 + k] * th[k];
            b2 += sew[47 + k] * th[k];
        }
        sdzb[t * 3 + 0] = b0;
        sdzb[t * 3 + 1] = b1;
        sdzb[t * 3 + 2] = b2;
    }

    __syncthreads();

    // ---- P3b: coalesced NT stores of the three small streams ----
    if (rem >= RPB) {
        if (t < RPB * 3 / 4) {   // 96 f32x4 per stream
            __builtin_nontemporal_store(((const f32x4*)sz)[t],
                (f32x4*)(out + (size_t)base * 3) + t);
            __builtin_nontemporal_store(((const f32x4*)sdz)[t],
                (f32x4*)(out + 3 * (size_t)nrows + (size_t)base * 3) + t);
            __builtin_nontemporal_store(((const f32x4*)sdzb)[t],
                (f32x4*)(out + 6 * (size_t)nrows + (size_t)base * 3) + t);
        }
    } else {
        for (int e = t; e < rem * 3; e += 256) {
            out[(size_t)base * 3 + e]                     = sz[e];
            out[3 * (size_t)nrows + (size_t)base * 3 + e] = sdz[e];
            out[6 * (size_t)nrows + (size_t)base * 3 + e] = sdzb[e];
        }
    }

    // ---- P4: xb NT-write stream ----
    float* __restrict__ xbout = out + 9 * (size_t)nrows;
    #pragma unroll 4
    for (int i = 0; i < RPB / 8; ++i) {
        const int r2  = i * 8 + half;
        const int row = base + r2;
        if (row >= nrows) continue;
        const float z0 = sz[r2 * 3 + 0];
        const float z1 = sz[r2 * 3 + 1];
        const float z2 = sz[r2 * 3 + 2];
        f32x4 v;
        v.x = jd0.x*z0 + jd0.y*z1 + jd0.z*z2 + jd0.w;
        v.y = jd1.x*z0 + jd1.y*z1 + jd1.z*z2 + jd1.w;
        v.z = jd2.x*z0 + jd2.y*z1 + jd2.z*z2 + jd2.w;
        v.w = jd3.x*z0 + jd3.y*z1 + jd3.z*z2 + jd3.w;
        __builtin_nontemporal_store(v, (f32x4*)(xbout + (size_t)row * D) + lane);
    }

    // ---- P5: dxb NT-write stream ----
    float* __restrict__ dxbout = out + 137 * (size_t)nrows;
    #pragma unroll 4
    for (int i = 0; i < RPB / 8; ++i) {
        const int r2  = i * 8 + half;
        const int row = base + r2;
        if (row >= nrows) continue;
        const float b0 = sdzb[r2 * 3 + 0];
        const float b1 = sdzb[r2 * 3 + 1];
        const float b2 = sdzb[r2 * 3 + 2];
        f32x4 v;
        v.x = jd0.x*b0 + jd0.y*b1 + jd0.z*b2;
        v.y = jd1.x*b0 + jd1.y*b1 + jd1.z*b2;
        v.z = jd2.x*b0 + jd2.y*b1 + jd2.z*b2;
        v.w = jd3.x*b0 + jd3.y*b1 + jd3.z*b2;
        __builtin_nontemporal_store(v, (f32x4*)(dxbout + (size_t)row * D) + lane);
    }
}

extern "C" void kernel_launch(void* const* d_in, const int* in_sizes, int n_in,
                              void* d_out, int out_size, void* d_ws, size_t ws_size,
                              hipStream_t stream) {
    const float* x   = (const float*)d_in[0];
    const float* dx  = (const float*)d_in[1];
    const float* We1 = (const float*)d_in[2];
    const float* be1 = (const float*)d_in[3];
    const float* We2 = (const float*)d_in[4];
    const float* be2 = (const float*)d_in[5];
    const float* We3 = (const float*)d_in[6];
    const float* be3 = (const float*)d_in[7];
    const float* Wd1 = (const float*)d_in[8];
    const float* bd1 = (const float*)d_in[9];
    const float* Wd2 = (const float*)d_in[10];
    const float* bd2 = (const float*)d_in[11];
    const float* Wd3 = (const float*)d_in[12];
    const float* bd3 = (const float*)d_in[13];
    const float* EW  = (const float*)d_in[14];
    const float* Eb  = (const float*)d_in[15];

    float* ws  = (float*)d_ws;
    float* out = (float*)d_out;
    const int nrows = in_sizes[0] / D;             // 262144
    const int nblk  = (nrows + RPB - 1) / RPB;     // 2048

    fuse_weights<<<1, 256, 0, stream>>>(We1, be1, We2, be2, We3, be3,
                                        Wd1, bd1, Wd2, bd2, Wd3, bd3, ws);

    sindy_all<<<nblk, 256, 0, stream>>>(x, dx, EW, Eb, ws, out, nrows);
}

// Round 14
// 108.203 us; speedup vs baseline: 1.1341x; 1.1306x over previous
//
#include <hip/hip_runtime.h>

#define D 128
#define RPB 128   // rows per block

typedef float f32x4 __attribute__((ext_vector_type(4)));

// ---------------------------------------------------------------------------
// DPP half-wave (32-lane) sum. Pure VALU (no DS pipe): row_shr 1,2,4,8 then
// row_bcast:15 into rows 1,3. Result valid in wave-lanes 31 and 63.
// [R7 A/B: replacing the ds_swizzle butterfly with DPP was +12us.]
// ---------------------------------------------------------------------------
__device__ __forceinline__ float dpp_half_sum(float v) {
    #define DPP_STEP(ctrl, rowmask)                                           \
        v += __int_as_float(__builtin_amdgcn_update_dpp(                      \
                 0, __float_as_int(v), (ctrl), (rowmask), 0xF, true))
    DPP_STEP(0x111, 0xF);   // row_shr:1
    DPP_STEP(0x112, 0xF);   // row_shr:2
    DPP_STEP(0x114, 0xF);   // row_shr:4
    DPP_STEP(0x118, 0xF);   // row_shr:8  -> lane15 of each 16-row has row sum
    DPP_STEP(0x142, 0xA);   // row_bcast:15 -> rows 1,3 add prev row's lane15
    #undef DPP_STEP
    return v;               // lanes 31, 63 hold their half's sum
}

// ---------------------------------------------------------------------------
// Kernel 0 (one block): fold the linear chains into ws.
//   ws[0..383]    : J_enc [3][128]  = We3@We2@We1
//   ws[384..386]  : b_enc [3]       = We3@(We2@be1 + be2) + be3
//   ws[512..1023] : J_dec4 [128][4] = (J_dec[c][0..2], b_dec[c])
// [R9 A/B: folding per-block instead costs ~20us; 1-block kernel is cheap.]
// ---------------------------------------------------------------------------
__global__ __launch_bounds__(256) void fuse_weights(
    const float* __restrict__ We1, const float* __restrict__ be1,
    const float* __restrict__ We2, const float* __restrict__ be2,
    const float* __restrict__ We3, const float* __restrict__ be3,
    const float* __restrict__ Wd1, const float* __restrict__ bd1,
    const float* __restrict__ Wd2, const float* __restrict__ bd2,
    const float* __restrict__ Wd3, const float* __restrict__ bd3,
    float* __restrict__ ws)
{
    __shared__ float A1[3][64];   // We3@We2
    __shared__ float B1[64][3];   // Wd2@Wd1
    __shared__ float t2d[64];     // Wd2@bd1 + bd2
    const int t = threadIdx.x;

    if (t < 192) {
        {   int r = t >> 6, c = t & 63;
            float s = 0.f;
            #pragma unroll 8
            for (int i = 0; i < 32; ++i) s += We3[r * 32 + i] * We2[i * 64 + c];
            A1[r][c] = s;
        }
        {   int o = t / 3, l = t - o * 3;
            float s = 0.f;
            #pragma unroll 8
            for (int i = 0; i < 32; ++i) s += Wd2[o * 32 + i] * Wd1[i * 3 + l];
            B1[o][l] = s;
        }
    } else {
        int i = t - 192;
        float s = bd2[i];
        #pragma unroll 8
        for (int j = 0; j < 32; ++j) s += Wd2[i * 32 + j] * bd1[j];
        t2d[i] = s;
    }
    __syncthreads();

    for (int e = t; e < 3 * D; e += 256) {
        int r = e >> 7, c = e & 127;
        float s = 0.f;
        #pragma unroll 8
        for (int j = 0; j < 64; ++j) s += A1[r][j] * We1[j * D + c];
        ws[e] = s;
    }
    if (t < 3) {
        float s = be3[t];
        #pragma unroll 8
        for (int j = 0; j < 64; ++j) s += A1[t][j] * be1[j];
        #pragma unroll 8
        for (int i = 0; i < 32; ++i) s += We3[t * 32 + i] * be2[i];
        ws[384 + t] = s;
    }
    if (t < 128) {
        float s0 = 0.f, s1 = 0.f, s2 = 0.f, sb = bd3[t];
        #pragma unroll 8
        for (int j = 0; j < 64; ++j) {
            float w = Wd3[t * 64 + j];
            s0 += w * B1[j][0];
            s1 += w * B1[j][1];
            s2 += w * B1[j][2];
            sb += w * t2d[j];
        }
        ws[512 + t * 4 + 0] = s0;
        ws[512 + t * 4 + 1] = s1;
        ws[512 + t * 4 + 2] = s2;
        ws[512 + t * 4 + 3] = sb;
    }
}

// ---------------------------------------------------------------------------
// Main kernel (R11, best measured = 110.0us): 128 contiguous rows per block.
//   P1: x  -> z   (coalesced PLAIN read [L3-retained across graph replays],
//                  DPP reduce [VALU], z -> LDS)
//   P2: dx -> dz  (same)
//   P3: theta/dzb row-per-thread, dzb -> LDS
//   P3b: z/dz/dzb stored coalesced (NT) from LDS as f32x4 bursts
//   P4: xb NT-write stream   P5: dxb NT-write stream
// A/B-mapped NT matrix: {plainL+ntS}=110 < {ntL+ntS}=113 < {plainL+plainS}
// ~123 < {ntL+plainS untested}. Plain loads exploit ~50% L3 replay hits
// (R8: FETCH=134MB); NT stores keep 278MB of writes from thrashing L3.
// Output layout: z@0 [N,3], dz@3N, dzb@6N, xb@9N [N,128], dxb@137N [N,128]
// ---------------------------------------------------------------------------
__global__ __launch_bounds__(256) void sindy_all(
    const float* __restrict__ x, const float* __restrict__ dx,
    const float* __restrict__ EW, const float* __restrict__ Eb,
    const float* __restrict__ ws, float* __restrict__ out, int nrows)
{
    __shared__ alignas(16) float sz[RPB * 3];     // z   [128][3]
    __shared__ alignas(16) float sdz[RPB * 3];    // dz  [128][3]
    __shared__ alignas(16) float sdzb[RPB * 3];   // dzb [128][3]
    __shared__ alignas(16) float sew[69];         // EW[66], Eb[3]

    const int t    = threadIdx.x;
    const int lane = t & 31;
    const int half = t >> 5;

    if (t < 69) sew[t] = (t < 66) ? EW[t] : Eb[t - 66];

    const f32x4 je0 = *((const f32x4*)(ws +   0) + lane);
    const f32x4 je1 = *((const f32x4*)(ws + 128) + lane);
    const f32x4 je2 = *((const f32x4*)(ws + 256) + lane);
    const float benc0 = ws[384], benc1 = ws[385], benc2 = ws[386];
    const f32x4 jd0 = *((const f32x4*)(ws + 512) + lane * 4 + 0);
    const f32x4 jd1 = *((const f32x4*)(ws + 512) + lane * 4 + 1);
    const f32x4 jd2 = *((const f32x4*)(ws + 512) + lane * 4 + 2);
    const f32x4 jd3 = *((const f32x4*)(ws + 512) + lane * 4 + 3);

    const int base = blockIdx.x * RPB;
    const int rem  = nrows - base;

    // ---- P1: x -> z (LDS) ----
    #pragma unroll 4
    for (int i = 0; i < RPB / 8; ++i) {
        const int r2  = i * 8 + half;
        const int row = base + r2;
        if (row >= nrows) continue;
        const f32x4 xv = ((const f32x4*)(x + (size_t)row * D))[lane];
        float z0 = je0.x*xv.x + je0.y*xv.y + je0.z*xv.z + je0.w*xv.w;
        float z1 = je1.x*xv.x + je1.y*xv.y + je1.z*xv.z + je1.w*xv.w;
        float z2 = je2.x*xv.x + je2.y*xv.y + je2.z*xv.z + je2.w*xv.w;
        z0 = dpp_half_sum(z0);
        z1 = dpp_half_sum(z1);
        z2 = dpp_half_sum(z2);
        if (lane == 31) {
            sz[r2 * 3 + 0] = z0 + benc0;
            sz[r2 * 3 + 1] = z1 + benc1;
            sz[r2 * 3 + 2] = z2 + benc2;
        }
    }

    // ---- P2: dx -> dz (LDS) ----
    #pragma unroll 4
    for (int i = 0; i < RPB / 8; ++i) {
        const int r2  = i * 8 + half;
        const int row = base + r2;
        if (row >= nrows) continue;
        const f32x4 dv = ((const f32x4*)(dx + (size_t)row * D))[lane];
        float d0 = je0.x*dv.x + je0.y*dv.y + je0.z*dv.z + je0.w*dv.w;
        float d1 = je1.x*dv.x + je1.y*dv.y + je1.z*dv.z + je1.w*dv.w;
        float d2 = je2.x*dv.x + je2.y*dv.y + je2.z*dv.z + je2.w*dv.w;
        d0 = dpp_half_sum(d0);
        d1 = dpp_half_sum(d1);
        d2 = dpp_half_sum(d2);
        if (lane == 31) {
            sdz[r2 * 3 + 0] = d0;
            sdz[r2 * 3 + 1] = d1;
            sdz[r2 * 3 + 2] = d2;
        }
    }

    __syncthreads();

    // ---- P3: theta/dzb, one row per thread ----
    if (t < RPB && t < rem) {
        const float z0 = sz[t * 3 + 0];
        const float z1 = sz[t * 3 + 1];
        const float z2 = sz[t * 3 + 2];

        const float q00 = z0*z0, q01 = z0*z1, q02 = z0*z2;
        const float q11 = z1*z1, q12 = z1*z2, q22 = z2*z2;
        float th[19];
        th[0]=z0;  th[1]=z1;  th[2]=z2;
        th[3]=q00; th[4]=q01; th[5]=q02; th[6]=q11; th[7]=q12; th[8]=q22;
        th[9]=q00*z0;  th[10]=q00*z1; th[11]=q00*z2;
        th[12]=q11*z0; th[13]=q12*z0; th[14]=q22*z0;
        th[15]=q11*z1; th[16]=q11*z2; th[17]=q22*z1; th[18]=q22*z2;

        float b0 = sew[66] + sew[0]  + sew[1]  + sew[2];
        float b1 = sew[67] + sew[22] + sew[23] + sew[24];
        float b2 = sew[68] + sew[44] + sew[45] + sew[46];
        #pragma unroll
        for (int k = 0; k < 19; ++k) {
            b0 += sew[3  + k] * th[k];
            b1 += sew[25 + k] * th[k];
            b2 += sew[47 + k] * th[k];
        }
        sdzb[t * 3 + 0] = b0;
        sdzb[t * 3 + 1] = b1;
        sdzb[t * 3 + 2] = b2;
    }

    __syncthreads();

    // ---- P3b: coalesced NT stores of the three small streams ----
    if (rem >= RPB) {
        if (t < RPB * 3 / 4) {   // 96 f32x4 per stream
            __builtin_nontemporal_store(((const f32x4*)sz)[t],
                (f32x4*)(out + (size_t)base * 3) + t);
            __builtin_nontemporal_store(((const f32x4*)sdz)[t],
                (f32x4*)(out + 3 * (size_t)nrows + (size_t)base * 3) + t);
            __builtin_nontemporal_store(((const f32x4*)sdzb)[t],
                (f32x4*)(out + 6 * (size_t)nrows + (size_t)base * 3) + t);
        }
    } else {
        for (int e = t; e < rem * 3; e += 256) {
            out[(size_t)base * 3 + e]                     = sz[e];
            out[3 * (size_t)nrows + (size_t)base * 3 + e] = sdz[e];
            out[6 * (size_t)nrows + (size_t)base * 3 + e] = sdzb[e];
        }
    }

    // ---- P4: xb NT-write stream ----
    float* __restrict__ xbout = out + 9 * (size_t)nrows;
    #pragma unroll 4
    for (int i = 0; i < RPB / 8; ++i) {
        const int r2  = i * 8 + half;
        const int row = base + r2;
        if (row >= nrows) continue;
        const float z0 = sz[r2 * 3 + 0];
        const float z1 = sz[r2 * 3 + 1];
        const float z2 = sz[r2 * 3 + 2];
        f32x4 v;
        v.x = jd0.x*z0 + jd0.y*z1 + jd0.z*z2 + jd0.w;
        v.y = jd1.x*z0 + jd1.y*z1 + jd1.z*z2 + jd1.w;
        v.z = jd2.x*z0 + jd2.y*z1 + jd2.z*z2 + jd2.w;
        v.w = jd3.x*z0 + jd3.y*z1 + jd3.z*z2 + jd3.w;
        __builtin_nontemporal_store(v, (f32x4*)(xbout + (size_t)row * D) + lane);
    }

    // ---- P5: dxb NT-write stream ----
    float* __restrict__ dxbout = out + 137 * (size_t)nrows;
    #pragma unroll 4
    for (int i = 0; i < RPB / 8; ++i) {
        const int r2  = i * 8 + half;
        const int row = base + r2;
        if (row >= nrows) continue;
        const float b0 = sdzb[r2 * 3 + 0];
        const float b1 = sdzb[r2 * 3 + 1];
        const float b2 = sdzb[r2 * 3 + 2];
        f32x4 v;
        v.x = jd0.x*b0 + jd0.y*b1 + jd0.z*b2;
        v.y = jd1.x*b0 + jd1.y*b1 + jd1.z*b2;
        v.z = jd2.x*b0 + jd2.y*b1 + jd2.z*b2;
        v.w = jd3.x*b0 + jd3.y*b1 + jd3.z*b2;
        __builtin_nontemporal_store(v, (f32x4*)(dxbout + (size_t)row * D) + lane);
    }
}

extern "C" void kernel_launch(void* const* d_in, const int* in_sizes, int n_in,
                              void* d_out, int out_size, void* d_ws, size_t ws_size,
                              hipStream_t stream) {
    const float* x   = (const float*)d_in[0];
    const float* dx  = (const float*)d_in[1];
    const float* We1 = (const float*)d_in[2];
    const float* be1 = (const float*)d_in[3];
    const float* We2 = (const float*)d_in[4];
    const float* be2 = (const float*)d_in[5];
    const float* We3 = (const float*)d_in[6];
    const float* be3 = (const float*)d_in[7];
    const float* Wd1 = (const float*)d_in[8];
    const float* bd1 = (const float*)d_in[9];
    const float* Wd2 = (const float*)d_in[10];
    const float* bd2 = (const float*)d_in[11];
    const float* Wd3 = (const float*)d_in[12];
    const float* bd3 = (const float*)d_in[13];
    const float* EW  = (const float*)d_in[14];
    const float* Eb  = (const float*)d_in[15];

    float* ws  = (float*)d_ws;
    float* out = (float*)d_out;
    const int nrows = in_sizes[0] / D;             // 262144
    const int nblk  = (nrows + RPB - 1) / RPB;     // 2048

    fuse_weights<<<1, 256, 0, stream>>>(We1, be1, We2, be2, We3, be3,
                                        Wd1, bd1, Wd2, bd2, Wd3, bd3, ws);

    sindy_all<<<nblk, 256, 0, stream>>>(x, dx, EW, Eb, ws, out, nrows);
}